// Round 1
// baseline (440.010 us; speedup 1.0000x reference)
//
#include <hip/hip_runtime.h>
#include <math.h>

#define BB 32
#define CC 4
#define HH 64
#define WW 512
#define HW (HH * WW)

// ---------------- softmax over W (last axis), one wave (64 lanes) per row ----------------
__global__ __launch_bounds__(256) void softmax_rows(const float* __restrict__ in,
                                                    float* __restrict__ out) {
    const int gwave = (blockIdx.x * 256 + threadIdx.x) >> 6;  // global wave id = row id
    const int lane  = threadIdx.x & 63;
    if (gwave >= BB * CC * HH) return;

    const float4* rowv = reinterpret_cast<const float4*>(in + (size_t)gwave * WW);
    float4* outv       = reinterpret_cast<float4*>(out + (size_t)gwave * WW);

    float4 a = rowv[lane];
    float4 b = rowv[lane + 64];

    float m = fmaxf(fmaxf(fmaxf(a.x, a.y), fmaxf(a.z, a.w)),
                    fmaxf(fmaxf(b.x, b.y), fmaxf(b.z, b.w)));
    #pragma unroll
    for (int off = 32; off; off >>= 1) m = fmaxf(m, __shfl_xor(m, off));

    a.x = expf(a.x - m); a.y = expf(a.y - m); a.z = expf(a.z - m); a.w = expf(a.w - m);
    b.x = expf(b.x - m); b.y = expf(b.y - m); b.z = expf(b.z - m); b.w = expf(b.w - m);

    float s = (a.x + a.y + a.z + a.w) + (b.x + b.y + b.z + b.w);
    #pragma unroll
    for (int off = 32; off; off >>= 1) s += __shfl_xor(s, off);

    const float inv = 1.0f / s;
    a.x *= inv; a.y *= inv; a.z *= inv; a.w *= inv;
    b.x *= inv; b.y *= inv; b.z *= inv; b.w *= inv;
    outv[lane]      = a;
    outv[lane + 64] = b;
}

// ---------------- fused: depthwise gaussian conv + bilateral condense + compat ----------------
// one block per (b, h); 512 threads = one per w; each thread handles all 4 classes
__global__ __launch_bounds__(512) void crf_fused(const float* __restrict__ U,
                                                 const float* __restrict__ M,
                                                 const float* __restrict__ BF,
                                                 float* __restrict__ out,
                                                 float k1, float k2, float k4, float k5) {
    __shared__ float u_lds[CC][3][WW + 4];
    __shared__ float m_lds[3][WW + 4];

    const int bh = blockIdx.x;
    const int b  = bh >> 6;   // / HH
    const int h  = bh & 63;   // % HH
    const int t  = threadIdx.x;

    // stage 3 rows (h-1, h, h+1) of unary (4 classes) and mask, zero-padded
    #pragma unroll
    for (int r = 0; r < 3; ++r) {
        const int hr = h + r - 1;
        const bool v = (hr >= 0) && (hr < HH);
        #pragma unroll
        for (int c = 0; c < CC; ++c)
            u_lds[c][r][2 + t] = v ? U[(((size_t)b * CC + c) * HH + hr) * WW + t] : 0.0f;
        m_lds[r][2 + t] = v ? M[((size_t)b * HH + hr) * WW + t] : 0.0f;
    }
    if (t < 2) {
        #pragma unroll
        for (int r = 0; r < 3; ++r) {
            #pragma unroll
            for (int c = 0; c < CC; ++c) {
                u_lds[c][r][t] = 0.0f;
                u_lds[c][r][WW + 2 + t] = 0.0f;
            }
            m_lds[r][t] = 0.0f;
            m_lds[r][WW + 2 + t] = 0.0f;
        }
    }
    __syncthreads();

    // 14 non-center taps: (row r in 0..2 => h+r-1), (col da in 0..4 => lds col = t + da)
    const int   rz[14] = {0,0,0,0,0, 1,1,1,1, 2,2,2,2,2};
    const int   ra[14] = {0,1,2,3,4, 0,1,3,4, 0,1,2,3,4};
    const float kw[14] = {k5,k2,k1,k2,k5, k4,k1,k1,k4, k5,k2,k1,k2,k5};

    const float mc = m_lds[1][2 + t];  // center mask

    float ang[CC], bi[CC], uc[CC];
    #pragma unroll
    for (int c = 0; c < CC; ++c) {
        const float* bfp = BF + (((size_t)b * CC + c) * 14) * HW + (size_t)h * WW + t;
        float a = 0.0f, cd = 0.0f;
        #pragma unroll
        for (int n = 0; n < 14; ++n) {
            const float uv = u_lds[c][rz[n]][t + ra[n]];
            const float mv = m_lds[rz[n]][t + ra[n]];
            a = fmaf(kw[n], uv, a);
            cd = fmaf(bfp[(size_t)n * HW], uv * mv, cd);
        }
        ang[c] = a;
        bi[c]  = cd * mc * a;     // condensed * lidar_mask * bi_ang (bi_ang == ang)
        uc[c]  = u_lds[c][1][2 + t];
    }

    const float sa = ang[0] + ang[1] + ang[2] + ang[3];
    const float sb = bi[0] + bi[1] + bi[2] + bi[3];

    #pragma unroll
    for (int c = 0; c < CC; ++c) {
        const float pw = 0.02f * (sa - ang[c]) + 0.1f * (sb - bi[c]);
        out[(((size_t)b * CC + c) * HH + h) * WW + t] = uc[c] + pw;
    }
}

extern "C" void kernel_launch(void* const* d_in, const int* in_sizes, int n_in,
                              void* d_out, int out_size, void* d_ws, size_t ws_size,
                              hipStream_t stream) {
    const float* x    = (const float*)d_in[0];
    const float* mask = (const float*)d_in[1];
    const float* bf   = (const float*)d_in[2];
    float* out = (float*)d_out;
    float* U   = (float*)d_ws;  // 16 MB unary scratch

    // gaussian weights, exact f64 -> f32 like numpy
    const double ts2 = 2.0 * 0.9 * 0.9;
    const float k1 = (float)exp(-1.0 / ts2);
    const float k2 = (float)exp(-2.0 / ts2);
    const float k4 = (float)exp(-4.0 / ts2);
    const float k5 = (float)exp(-5.0 / ts2);

    const int rows = BB * CC * HH;             // 8192 rows
    const dim3 sgrid((rows + 3) / 4), sblk(256);
    const dim3 fgrid(BB * HH), fblk(512);      // 2048 blocks

    // iter 1: x -> U -> out ; iters 2,3: out -> U -> out (fused kernel never reads 'out')
    softmax_rows<<<sgrid, sblk, 0, stream>>>(x, U);
    crf_fused<<<fgrid, fblk, 0, stream>>>(U, mask, bf, out, k1, k2, k4, k5);

    softmax_rows<<<sgrid, sblk, 0, stream>>>(out, U);
    crf_fused<<<fgrid, fblk, 0, stream>>>(U, mask, bf, out, k1, k2, k4, k5);

    softmax_rows<<<sgrid, sblk, 0, stream>>>(out, U);
    crf_fused<<<fgrid, fblk, 0, stream>>>(U, mask, bf, out, k1, k2, k4, k5);
}